// Round 6
// baseline (213.997 us; speedup 1.0000x reference)
//
#include <hip/hip_runtime.h>
#include <hip/hip_fp16.h>
#include <hip/hip_cooperative_groups.h>
#include <stdint.h>

namespace cg = cooperative_groups;

// out[c,b,g] = sum_{s<8} prod_{l<3} x[b, I[c,g,s,l]]
//
// R6: single cooperative kernel. Phase 1 = full-machine cold stream (I pack
// int32->u16 + f16 x-image build into ws); grid.sync(); Phase 2 = R5's warm
// clause evaluation. Removes the P->M launch gap and tail/ramp serialization
// that R5's split exposed (R5 bought only 1.6 us because P's drain + M's
// ramp re-serialized what the split saved).
#define Cc 16
#define Gg 8192
#define Ss 8
#define Ll 3
#define Bb 32

#define BH 4                   // b-rows per slice (f16) -> 8 B per g column
#define NZ (Bb / BH)           // 8 slices
#define MTHREADS 512
#define NBLK 512               // 2 blocks/CU, exactly co-resident

// d_ws layout: [0, 512KB) f16 image xh[NZ][Gg][BH]; [512KB, +6.29MB) u16 I.
#define XH_BYTES  ((size_t)NZ * Gg * BH * 2)           // 524288
#define I16_OFF   XH_BYTES
#define I16_BYTES ((size_t)Cc * Gg * Ss * Ll * 2)      // 6291456

// ---- x-image build helper: thread tt in [0, 16384) packs 4 g-columns of
// slice zh = tt>>11 into the f16 image (uint2 per column = b0b1, b2b3).
__device__ __forceinline__ void build_ximage(const float* __restrict__ x,
                                             uint4* __restrict__ ws4, int tt) {
    const int zh = tt >> 11;
    const int gg = (tt & 2047) << 2;               // 4 consecutive g
    const float* xr = x + (size_t)(4 * zh) * Gg + gg;
    float4 f0 = *(const float4*)&xr[0];
    float4 f1 = *(const float4*)&xr[Gg];
    float4 f2 = *(const float4*)&xr[2 * (size_t)Gg];
    float4 f3 = *(const float4*)&xr[3 * (size_t)Gg];
    __half2 lo0 = __floats2half2_rn(f0.x, f1.x), hi0 = __floats2half2_rn(f2.x, f3.x);
    __half2 lo1 = __floats2half2_rn(f0.y, f1.y), hi1 = __floats2half2_rn(f2.y, f3.y);
    __half2 lo2 = __floats2half2_rn(f0.z, f1.z), hi2 = __floats2half2_rn(f2.z, f3.z);
    __half2 lo3 = __floats2half2_rn(f0.w, f1.w), hi3 = __floats2half2_rn(f2.w, f3.w);
    uint4 w0 = make_uint4(*(uint32_t*)&lo0, *(uint32_t*)&hi0,
                          *(uint32_t*)&lo1, *(uint32_t*)&hi1);
    uint4 w1 = make_uint4(*(uint32_t*)&lo2, *(uint32_t*)&hi2,
                          *(uint32_t*)&lo3, *(uint32_t*)&hi3);
    uint4* dst = ws4 + ((size_t)zh << 12) + ((size_t)(tt & 2047) << 1);
    dst[0] = w0;
    dst[1] = w1;
}

// Evaluate one (c,g): 24 u16 indices in 3 uint4 regs; 24 natural-layout
// ds_read_b64 gathers. Two 12-gather half-batches cap live registers.
__device__ __forceinline__ void clause_eval16(const uint2* __restrict__ xl2,
                                              const uint4 q[3], float acc[4]) {
    const uint32_t u[12] = {q[0].x, q[0].y, q[0].z, q[0].w,
                            q[1].x, q[1].y, q[1].z, q[1].w,
                            q[2].x, q[2].y, q[2].z, q[2].w};
    #pragma unroll
    for (int h = 0; h < 2; ++h) {
        uint2 r[12];
        #pragma unroll
        for (int m = 0; m < 6; ++m) {
            const uint32_t w = u[6 * h + m];
            r[2 * m]     = xl2[w & 0xffffu];           // independent ds_read_b64
            r[2 * m + 1] = xl2[w >> 16];
        }
        #pragma unroll
        for (int s = 0; s < 4; ++s) {
            const uint2 ra = r[3 * s + 0];
            const uint2 rb = r[3 * s + 1];
            const uint2 rd = r[3 * s + 2];
            __half2 p0 = __hmul2(__hmul2(*(const __half2*)&ra.x,
                                         *(const __half2*)&rb.x),
                                 *(const __half2*)&rd.x);   // b0,b1
            __half2 p1 = __hmul2(__hmul2(*(const __half2*)&ra.y,
                                         *(const __half2*)&rb.y),
                                 *(const __half2*)&rd.y);   // b2,b3
            float2 f0 = __half22float2(p0);
            float2 f1 = __half22float2(p1);
            acc[0] += f0.x;
            acc[1] += f0.y;
            acc[2] += f1.x;
            acc[3] += f1.y;
        }
    }
}

#define QLOAD(QB, CV, GV)                                                     \
    {                                                                         \
        const uint4* p =                                                      \
            (const uint4*)(i16 + ((size_t)(CV) * Gg + (GV)) * (Ss * Ll));     \
        QB[0] = p[0]; QB[1] = p[1]; QB[2] = p[2];                             \
    }

#define EVAL_STORE(QB, CV, GV)                                                \
    {                                                                         \
        float acc[4] = {0.f, 0.f, 0.f, 0.f};                                  \
        clause_eval16(xl2, QB, acc);                                          \
        float* op = out + ((size_t)((CV) * Bb + BH * zh)) * Gg + (GV);        \
        __builtin_nontemporal_store(acc[0], &op[0]);                          \
        __builtin_nontemporal_store(acc[1], &op[(size_t)Gg]);                 \
        __builtin_nontemporal_store(acc[2], &op[2 * (size_t)Gg]);             \
        __builtin_nontemporal_store(acc[3], &op[3 * (size_t)Gg]);             \
    }

// ---- Phase-2 body (identical mapping to R5's clause_m, verified passing).
__device__ __forceinline__ void phase2_eval(const uint4* __restrict__ xh4,
                                            const ushort* __restrict__ i16,
                                            float* __restrict__ out,
                                            uint4* __restrict__ xl4) {
    const int tid = threadIdx.x;
    const int lb = (blockIdx.x & 7) * 64 + (blockIdx.x >> 3);
    const int zh = lb & (NZ - 1);
    const int combo = lb >> 3;
    const int gc = combo & 7;
    const int cp = combo >> 3;
    const int gbase = gc * 1024;
    const int c0 = 2 * cp, c1 = 2 * cp + 1;
    const int g0 = gbase + tid;
    const int g1 = gbase + MTHREADS + tid;

    // Stage loads: 8 x uint4 = the block's 64 KB slice (pure copy, warm).
    const uint4* src = xh4 + ((size_t)zh << 12);
    uint4 st[8];
    #pragma unroll
    for (int i = 0; i < 8; ++i) st[i] = src[tid + i * MTHREADS];

    // All-q prefetch (12 x uint4, warm) behind the stage loads.
    uint4 qA[3], qB[3], qC[3], qD[3];
    QLOAD(qA, c0, g0)
    QLOAD(qB, c0, g1)
    QLOAD(qC, c1, g0)
    QLOAD(qD, c1, g1)

    #pragma unroll
    for (int i = 0; i < 8; ++i) xl4[tid + i * MTHREADS] = st[i];

    __syncthreads();

    const uint2* xl2 = (const uint2*)xl4;
    EVAL_STORE(qA, c0, g0)
    EVAL_STORE(qB, c0, g1)
    EVAL_STORE(qC, c1, g0)
    EVAL_STORE(qD, c1, g1)
}

// ---- R6 fused cooperative kernel.
__global__ __launch_bounds__(MTHREADS, 4) void fused(
        const float* __restrict__ x, const uint4* __restrict__ I4,
        uint4* __restrict__ ws4, float* __restrict__ out) {
    __shared__ uint4 xl4[Gg / 2];                      // 64 KB
    const int t = blockIdx.x * MTHREADS + threadIdx.x; // [0, 262144)

    // Phase 1: I-pack — every thread packs 3 uint4 (entire 12.6 MB cold read
    // at full-machine MLP), wave-contiguous.
    {
        uint2* ow = (uint2*)((char*)ws4 + I16_OFF);
        #pragma unroll
        for (int i = 0; i < 3; ++i) {
            const int e = t + i * (NBLK * MTHREADS);
            uint4 v = I4[e];
            uint2 o;
            o.x = (v.x & 0xffffu) | (v.y << 16);       // order-preserving pack
            o.y = (v.z & 0xffffu) | (v.w << 16);
            ow[e] = o;
        }
    }
    // Phase 1b: x-image build (16384 threads; hides under the I-pack).
    if (t < 16384) build_ximage(x, ws4, t);

    __threadfence();                                   // device-scope release
    cg::this_grid().sync();                            // all ws writes visible

    // Phase 2: warm clause evaluation.
    phase2_eval(ws4, (const ushort*)((char*)ws4 + I16_OFF), out, xl4);
}

// ---- Fallback path A (R5 two-kernel, verified): if cooperative launch is
// unavailable under graph capture.
#define PB_X 64
#define PB_I 384
__global__ __launch_bounds__(256) void prepass(const float* __restrict__ x,
                                               const uint4* __restrict__ I4,
                                               uint4* __restrict__ ws4) {
    const int bid = blockIdx.x;
    if (bid < PB_X) {
        build_ximage(x, ws4, bid * 256 + threadIdx.x);
    } else {
        const int t = (bid - PB_X) * 256 + threadIdx.x;
        uint2* ow = (uint2*)((char*)ws4 + I16_OFF);
        #pragma unroll
        for (int i = 0; i < 8; ++i) {
            const int e = t + i * (PB_I * 256);
            uint4 v = I4[e];
            uint2 o;
            o.x = (v.x & 0xffffu) | (v.y << 16);
            o.y = (v.z & 0xffffu) | (v.w << 16);
            ow[e] = o;
        }
    }
}

__global__ __launch_bounds__(MTHREADS, 4) void clause_m(
        const uint4* __restrict__ xh4, const ushort* __restrict__ i16,
        float* __restrict__ out) {
    __shared__ uint4 xl4[Gg / 2];                      // 64 KB
    phase2_eval(xh4, i16, out, xl4);
}

// ---- Fallback path B (ws too small): direct global gather; slow but correct.
__global__ __launch_bounds__(256) void clause_kernel_direct(const float* __restrict__ x,
                                                            const int* __restrict__ I,
                                                            float* __restrict__ out) {
    const int tid = threadIdx.x;
    const int b = tid & 31;
    const int j = tid >> 5;
    const int g = blockIdx.x * 8 + j;
    const int c = blockIdx.y;

    const int* Icg = I + (size_t)(c * Gg + g) * (Ss * Ll);
    float sum = 0.f;
    #pragma unroll
    for (int s = 0; s < Ss; ++s) {
        float p0 = x[(size_t)b * Gg + Icg[3 * s + 0]];
        float p1 = x[(size_t)b * Gg + Icg[3 * s + 1]];
        float p2 = x[(size_t)b * Gg + Icg[3 * s + 2]];
        sum += p0 * p1 * p2;
    }
    out[(size_t)(c * Bb + b) * Gg + g] = sum;
}

extern "C" void kernel_launch(void* const* d_in, const int* in_sizes, int n_in,
                              void* d_out, int out_size, void* d_ws, size_t ws_size,
                              hipStream_t stream) {
    const float* x = (const float*)d_in[0];
    const int* I = (const int*)d_in[1];
    float* out = (float*)d_out;

    const size_t need = I16_OFF + I16_BYTES;           // ~6.82 MB
    if (ws_size >= need) {
        const float* xa = x;
        const uint4* I4 = (const uint4*)I;
        uint4* ws4 = (uint4*)d_ws;
        float* oa = out;
        void* args[] = {(void*)&xa, (void*)&I4, (void*)&ws4, (void*)&oa};
        hipError_t err = hipLaunchCooperativeKernel(
            (const void*)fused, dim3(NBLK), dim3(MTHREADS), args, 0, stream);
        if (err != hipSuccess) {                       // fallback: R5 path
            prepass<<<PB_X + PB_I, 256, 0, stream>>>(x, (const uint4*)I,
                                                     (uint4*)d_ws);
            clause_m<<<NBLK, MTHREADS, 0, stream>>>(
                (const uint4*)d_ws, (const ushort*)((char*)d_ws + I16_OFF), out);
        }
    } else {
        clause_kernel_direct<<<dim3(Gg / 8, Cc), 256, 0, stream>>>(x, I, out);
    }
}

// Round 7
// 78.550 us; speedup vs baseline: 2.7244x; 2.7244x over previous
//
#include <hip/hip_runtime.h>
#include <hip/hip_fp16.h>
#include <stdint.h>

// out[c,b,g] = sum_{s<8} prod_{l<3} x[b, I[c,g,s,l]]
//
// R7: MLP round. R3/R6 analysis: the ~11 us stage/q phase is L3-latency
// bound (L2 is invalidated at kernel start; ~320 KB/CU of L3 reads gated by
// in-flight capacity). Fix: 1024 thr x 512 blk = 2 blocks/CU x 32 waves/CU
// (double the latency-hiding waves), VGPR trimmed to fit the 64-reg budget
// (6-index gather half-batches, 2 evals/thread). Prepass (verified R5) kept:
// absorbs the cold-HBM stream and u16-packs I (halves q in-flight count).
#define Cc 16
#define Gg 8192
#define Ss 8
#define Ll 3
#define Bb 32

#define BH 4                   // b-rows per slice (f16) -> 8 B per g column
#define NZ (Bb / BH)           // 8 slices
#define MTHREADS 1024
#define NBLK 512

// d_ws layout: [0, 512KB) f16 image xh[NZ][Gg][BH]; [512KB, +6.29MB) u16 I.
#define XH_BYTES  ((size_t)NZ * Gg * BH * 2)           // 524288
#define I16_OFF   XH_BYTES
#define I16_BYTES ((size_t)Cc * Gg * Ss * Ll * 2)      // 6291456

// ---- Kernel P (verified R5): one streaming pass over the cold inputs.
//  blocks [0,64):   x-image build  xh[zh][g] = uint2{f16(b0,b1), f16(b2,b3)}
//  blocks [64,448): I pack int32 -> u16 (order-preserving), wave-contiguous
#define PB_X 64
#define PB_I 384
__global__ __launch_bounds__(256) void prepass(const float* __restrict__ x,
                                               const uint4* __restrict__ I4,
                                               uint4* __restrict__ ws4) {
    const int bid = blockIdx.x;
    if (bid < PB_X) {
        const int tt = bid * 256 + threadIdx.x;        // [0, 16384)
        const int zh = tt >> 11;                       // slice
        const int gg = (tt & 2047) << 2;               // 4 consecutive g
        const float* xr = x + (size_t)(4 * zh) * Gg + gg;
        float4 f0 = *(const float4*)&xr[0];
        float4 f1 = *(const float4*)&xr[Gg];
        float4 f2 = *(const float4*)&xr[2 * (size_t)Gg];
        float4 f3 = *(const float4*)&xr[3 * (size_t)Gg];
        __half2 lo0 = __floats2half2_rn(f0.x, f1.x), hi0 = __floats2half2_rn(f2.x, f3.x);
        __half2 lo1 = __floats2half2_rn(f0.y, f1.y), hi1 = __floats2half2_rn(f2.y, f3.y);
        __half2 lo2 = __floats2half2_rn(f0.z, f1.z), hi2 = __floats2half2_rn(f2.z, f3.z);
        __half2 lo3 = __floats2half2_rn(f0.w, f1.w), hi3 = __floats2half2_rn(f2.w, f3.w);
        uint4 w0 = make_uint4(*(uint32_t*)&lo0, *(uint32_t*)&hi0,
                              *(uint32_t*)&lo1, *(uint32_t*)&hi1);
        uint4 w1 = make_uint4(*(uint32_t*)&lo2, *(uint32_t*)&hi2,
                              *(uint32_t*)&lo3, *(uint32_t*)&hi3);
        uint4* dst = ws4 + ((size_t)zh << 12) + ((size_t)(tt & 2047) << 1);
        dst[0] = w0;                                   // 32 B/thread, coalesced
        dst[1] = w1;
    } else {
        const int t = (bid - PB_X) * 256 + threadIdx.x;
        uint2* ow = (uint2*)((char*)ws4 + I16_OFF);
        #pragma unroll
        for (int i = 0; i < 8; ++i) {
            const int e = t + i * (PB_I * 256);
            uint4 v = I4[e];
            uint2 o;
            o.x = (v.x & 0xffffu) | (v.y << 16);       // order-preserving pack
            o.y = (v.z & 0xffffu) | (v.w << 16);
            ow[e] = o;
        }
    }
}

// Evaluate one (c,g): 24 u16 indices in 3 uint4 regs; 24 natural-layout
// ds_read_b64 gathers in FOUR 6-gather batches (r[6] = 12 live VGPRs) to
// fit the 64-reg budget of 8 waves/EU.
__device__ __forceinline__ void clause_eval16(const uint2* __restrict__ xl2,
                                              const uint4 q[3], float acc[4]) {
    const uint32_t u[12] = {q[0].x, q[0].y, q[0].z, q[0].w,
                            q[1].x, q[1].y, q[1].z, q[1].w,
                            q[2].x, q[2].y, q[2].z, q[2].w};
    #pragma unroll
    for (int h = 0; h < 4; ++h) {                      // batch = 2 s-groups
        uint2 r[6];
        #pragma unroll
        for (int m = 0; m < 3; ++m) {
            const uint32_t w = u[3 * h + m];
            r[2 * m]     = xl2[w & 0xffffu];           // independent ds_read_b64
            r[2 * m + 1] = xl2[w >> 16];
        }
        #pragma unroll
        for (int s = 0; s < 2; ++s) {
            const uint2 ra = r[3 * s + 0];
            const uint2 rb = r[3 * s + 1];
            const uint2 rd = r[3 * s + 2];
            __half2 p0 = __hmul2(__hmul2(*(const __half2*)&ra.x,
                                         *(const __half2*)&rb.x),
                                 *(const __half2*)&rd.x);   // b0,b1
            __half2 p1 = __hmul2(__hmul2(*(const __half2*)&ra.y,
                                         *(const __half2*)&rb.y),
                                 *(const __half2*)&rd.y);   // b2,b3
            float2 f0 = __half22float2(p0);
            float2 f1 = __half22float2(p1);
            acc[0] += f0.x;
            acc[1] += f0.y;
            acc[2] += f1.x;
            acc[3] += f1.y;
        }
    }
}

#define QLOAD(QB, CV, GV)                                                     \
    {                                                                         \
        const uint4* p =                                                      \
            (const uint4*)(i16 + ((size_t)(CV) * Gg + (GV)) * (Ss * Ll));     \
        QB[0] = p[0]; QB[1] = p[1]; QB[2] = p[2];                             \
    }

#define EVAL_STORE(QB, CV, GV)                                                \
    {                                                                         \
        float acc[4] = {0.f, 0.f, 0.f, 0.f};                                  \
        clause_eval16(xl2, QB, acc);                                          \
        float* op = out + ((size_t)((CV) * Bb + BH * zh)) * Gg + (GV);        \
        __builtin_nontemporal_store(acc[0], &op[0]);                          \
        __builtin_nontemporal_store(acc[1], &op[(size_t)Gg]);                 \
        __builtin_nontemporal_store(acc[2], &op[2 * (size_t)Gg]);             \
        __builtin_nontemporal_store(acc[3], &op[3 * (size_t)Gg]);             \
    }

// ---- Kernel M: 512 blocks x 1024 threads = 2 blocks/CU, 32 waves/CU
// (8 waves/EU -> VGPR cap 64; current codegen measures 52). Per thread:
// 4 stage uint4 + 6 q uint4 all issued before any wait, then 2 evals.
__global__ __launch_bounds__(MTHREADS, 8) void clause_m(
        const uint4* __restrict__ xh4, const ushort* __restrict__ i16,
        float* __restrict__ out) {
    __shared__ uint4 xl4[Gg / 2];                      // 64 KB
    const int tid = threadIdx.x;

    // XCD-bijective swizzle (512 % 8 == 0): one c-pair per XCD.
    const int lb = (blockIdx.x & 7) * 64 + (blockIdx.x >> 3);
    const int zh = lb & (NZ - 1);
    const int combo = lb >> 3;
    const int gc = combo & 7;
    const int cp = combo >> 3;
    const int c0 = 2 * cp, c1 = 2 * cp + 1;
    const int g = gc * 1024 + tid;                     // one g per thread

    // Stage loads: 4 x uint4 = the block's 64 KB slice (pure copy, L3).
    const uint4* src = xh4 + ((size_t)zh << 12);
    uint4 st[4];
    #pragma unroll
    for (int i = 0; i < 4; ++i) st[i] = src[tid + i * MTHREADS];

    // q prefetch (6 x uint4) behind the stage loads.
    uint4 qA[3], qB[3];
    QLOAD(qA, c0, g)
    QLOAD(qB, c1, g)

    #pragma unroll
    for (int i = 0; i < 4; ++i) xl4[tid + i * MTHREADS] = st[i];

    __syncthreads();                                   // the ONE barrier

    const uint2* xl2 = (const uint2*)xl4;
    EVAL_STORE(qA, c0, g)
    EVAL_STORE(qB, c1, g)
}

// ---- Fallback (ws too small): direct global gather; slow but correct.
__global__ __launch_bounds__(256) void clause_kernel_direct(const float* __restrict__ x,
                                                            const int* __restrict__ I,
                                                            float* __restrict__ out) {
    const int tid = threadIdx.x;
    const int b = tid & 31;
    const int j = tid >> 5;
    const int g = blockIdx.x * 8 + j;
    const int c = blockIdx.y;

    const int* Icg = I + (size_t)(c * Gg + g) * (Ss * Ll);
    float sum = 0.f;
    #pragma unroll
    for (int s = 0; s < Ss; ++s) {
        float p0 = x[(size_t)b * Gg + Icg[3 * s + 0]];
        float p1 = x[(size_t)b * Gg + Icg[3 * s + 1]];
        float p2 = x[(size_t)b * Gg + Icg[3 * s + 2]];
        sum += p0 * p1 * p2;
    }
    out[(size_t)(c * Bb + b) * Gg + g] = sum;
}

extern "C" void kernel_launch(void* const* d_in, const int* in_sizes, int n_in,
                              void* d_out, int out_size, void* d_ws, size_t ws_size,
                              hipStream_t stream) {
    const float* x = (const float*)d_in[0];
    const int* I = (const int*)d_in[1];
    float* out = (float*)d_out;

    const size_t need = I16_OFF + I16_BYTES;           // ~6.82 MB
    if (ws_size >= need) {
        prepass<<<PB_X + PB_I, 256, 0, stream>>>(x, (const uint4*)I,
                                                 (uint4*)d_ws);
        clause_m<<<NBLK, MTHREADS, 0, stream>>>(
            (const uint4*)d_ws, (const ushort*)((char*)d_ws + I16_OFF), out);
    } else {
        clause_kernel_direct<<<dim3(Gg / 8, Cc), 256, 0, stream>>>(x, I, out);
    }
}